// Round 17
// baseline (138.291 us; speedup 1.0000x reference)
//
#include <hip/hip_runtime.h>

#define DEV static __device__ __forceinline__

typedef __attribute__((ext_vector_type(4))) float f32x4;
typedef __attribute__((ext_vector_type(16))) float f32x16;
typedef __attribute__((ext_vector_type(8))) __bf16 bfv8;
typedef __attribute__((ext_vector_type(8))) short s8v;
typedef __attribute__((ext_vector_type(4))) short s4v;

DEV short f2bf(float f) {
    unsigned u = __float_as_uint(f);
    u = (u + 0x7fffu + ((u >> 16) & 1u)) >> 16;
    return (short)u;
}
DEV float bf2f(short s) { return __uint_as_float(((unsigned)(unsigned short)s) << 16); }

DEV void gload16(const void* g, void* l) {
    __builtin_amdgcn_global_load_lds(
        (const __attribute__((address_space(1))) void*)g,
        (__attribute__((address_space(3))) void*)l, 16, 0, 0);
}

DEV f32x4 mfma16(bfv8 a, bfv8 b, f32x4 c) {
    return __builtin_amdgcn_mfma_f32_16x16x32_bf16(a, b, c, 0, 0, 0);
}
DEV f32x16 mfma32(bfv8 a, bfv8 b, f32x16 c) {
    return __builtin_amdgcn_mfma_f32_32x32x16_bf16(a, b, c, 0, 0, 0);
}

DEV float max3f(float a, float b, float c) {
    float d;
    asm("v_max3_f32 %0, %1, %2, %3" : "=v"(d) : "v"(a), "v"(b), "v"(c));
    return d;
}
DEV unsigned cvtpk(float lo, float hi) {
    unsigned w;
    asm("v_cvt_pk_bf16_f32 %0, %1, %2" : "=v"(w) : "v"(lo), "v"(hi));
    return w;
}

// LDS tile layout: [row][8 slots of 8 bf16], physical slot = logical slot ^ (row&7)
DEV bfv8 ldsfrag(const short* base, int row, int slog) {
    int sp = slog ^ (row & 7);
    return *reinterpret_cast<const bfv8*>(base + row * 64 + sp * 8);
}

// ---------------- f32 -> bf16 elementwise (8 elems/thread, exact-fit grid) ----
__global__ void k_cvt(const float* __restrict__ in, short* __restrict__ out, float s) {
    int i = blockIdx.x * blockDim.x + threadIdx.x;
    const float4* p = (const float4*)in + (size_t)i * 2;
    float4 a = p[0], b = p[1];
    s8v o;
    o[0] = f2bf(a.x * s); o[1] = f2bf(a.y * s); o[2] = f2bf(a.z * s); o[3] = f2bf(a.w * s);
    o[4] = f2bf(b.x * s); o[5] = f2bf(b.y * s); o[6] = f2bf(b.z * s); o[7] = f2bf(b.w * s);
    reinterpret_cast<s8v*>(out)[i] = o;
}

// ---------------- bias transform: bb[S,S] f32 -> bbt[(k>>3)][q][k&7] bf16 ------
// Dense layout for the 32x32 attn: lane (q, hi) loads s4v at
// ((k>>3)*2048 + q)*8 + 4*hi -> 512B contiguous per wave-load. LDS-tiled 64x64.
__global__ void k_cvtb(const float* __restrict__ in, short* __restrict__ out, float s) {
    __shared__ float tl[64][68];
    const int t = threadIdx.x;
    const int q0 = blockIdx.x * 64, c0 = blockIdx.y * 64;
    {
        int row = t >> 2, ch = t & 3;
        const float* src = in + (size_t)(q0 + row) * 2048 + c0 + ch * 16;
        float* dst = &tl[row][ch * 16];
#pragma unroll
        for (int j = 0; j < 4; j++) {
            float4 v = reinterpret_cast<const float4*>(src)[j];
            dst[4 * j + 0] = v.x; dst[4 * j + 1] = v.y;
            dst[4 * j + 2] = v.z; dst[4 * j + 3] = v.w;
        }
    }
    __syncthreads();
    const int c8 = t >> 5, qq = t & 31;
#pragma unroll
    for (int half = 0; half < 2; half++) {
        int q = qq + 32 * half;
        s8v o;
#pragma unroll
        for (int v = 0; v < 8; v++) o[v] = f2bf(tl[q][c8 * 8 + v] * s);
        *reinterpret_cast<s8v*>(out + ((size_t)((c0 >> 3) + c8) * 2048 + q0 + q) * 8) = o;
    }
}

// ---------------- all four W [1024x1024] f32 -> Wt [n][k] bf16 (z selects) -----
__global__ void k_transpose4(
    const float* __restrict__ W0, const float* __restrict__ W1,
    const float* __restrict__ W2, const float* __restrict__ W3,
    short* __restrict__ T0, short* __restrict__ T1,
    short* __restrict__ T2, short* __restrict__ T3, float s0)
{
    __shared__ float tl[32][33];
    const int z = blockIdx.z;
    const float* W = z == 0 ? W0 : z == 1 ? W1 : z == 2 ? W2 : W3;
    short* Wt = z == 0 ? T0 : z == 1 ? T1 : z == 2 ? T2 : T3;
    const float s = z == 0 ? s0 : 1.f;
    int tx = threadIdx.x & 31, ty = threadIdx.x >> 5;
    int nb = blockIdx.x * 32, kb = blockIdx.y * 32;
#pragma unroll
    for (int i = 0; i < 4; i++)
        tl[ty + i * 8][tx] = W[(kb + ty + i * 8) * 1024 + nb + tx];
    __syncthreads();
#pragma unroll
    for (int i = 0; i < 4; i++)
        Wt[(nb + ty + i * 8) * 1024 + kb + tx] = f2bf(tl[tx][ty + i * 8] * s);
}

// ---------------- GEMM epilogue (shared) --------------------------------------
// epi 0: bf16 [B,H,S,Hd]; epi 1: bf16 [B,H,Hd,S] (V~: within each 16-col group
// of V^T, col bits 3<->2 swapped so attn's contiguous A-frag reads match the
// in-register P slot order); epi 2: f32 row-major.
template <int EPI>
DEV void gemm_store(f32x4 a4, int gr, int gc, const float* bias, float bscale,
                    void* outp)
{
    const float bvl = bias[gc] * bscale;
    const int h = gc >> 6, d = gc & 63;
    if (EPI == 2) {
        float* O = (float*)outp;
#pragma unroll
        for (int r = 0; r < 4; r++) O[(gr + r) * 1024 + gc] = a4[r] + bvl;
    } else {
        const int b = gr >> 11, sr = gr & 2047;
        short* O = (short*)outp;
        if (EPI == 0) {
            int base = ((b * 16 + h) * 2048 + sr) * 64 + d;
#pragma unroll
            for (int r = 0; r < 4; r++) O[base + r * 64] = f2bf(a4[r] + bvl);
        } else {
            s4v vv;
#pragma unroll
            for (int r = 0; r < 4; r++) vv[r] = f2bf(a4[r] + bvl);
            const int s6 = sr & 63;
            const int qp = (sr & ~63) | (s6 & 51) | ((s6 & 4) << 1) | ((s6 & 8) >> 1);
            *reinterpret_cast<s4v*>(O + ((b * 16 + h) * 64 + d) * 2048 + qp) = vv;
        }
    }
}

// ---------------- GEMM core 64x128, double-buffered (4 waves 2Mx2N) -----------
template <int EPI>
DEV void gemm_body(const short* __restrict__ A, const short* __restrict__ Bt,
                   const float* __restrict__ bias, void* __restrict__ outp,
                   float bscale, int row0, int col0, short (*As)[64 * 64],
                   short (*Bs)[128 * 64])
{
    const int t = threadIdx.x, lane = t & 63;
    const int wv = t >> 6, wr = wv >> 1, wc = wv & 1;
    const int g = lane >> 4, c = lane & 15;

    const f32x4 z4 = {0.f, 0.f, 0.f, 0.f};
    f32x4 acc[2][4];
#pragma unroll
    for (int m = 0; m < 2; m++)
#pragma unroll
        for (int n = 0; n < 4; n++) acc[m][n] = z4;

    const short* Ap[2]; const short* Bp[4]; int Ad[2], Bd[4];
#pragma unroll
    for (int j = 0; j < 2; j++) {
        int idx = j * 256 + t;
        int row = idx >> 3, sl = ((idx & 7) ^ (row & 7)) * 8;
        Ap[j] = A + row0 * 1024 + row * 1024 + sl;
        Ad[j] = idx * 8;
    }
#pragma unroll
    for (int j = 0; j < 4; j++) {
        int idx = j * 256 + t;
        int row = idx >> 3, sl = ((idx & 7) ^ (row & 7)) * 8;
        Bp[j] = Bt + col0 * 1024 + row * 1024 + sl;
        Bd[j] = idx * 8;
    }
    auto stage = [&](int buf) {
#pragma unroll
        for (int j = 0; j < 2; j++) { gload16(Ap[j], &As[buf][Ad[j]]); Ap[j] += 64; }
#pragma unroll
        for (int j = 0; j < 4; j++) { gload16(Bp[j], &Bs[buf][Bd[j]]); Bp[j] += 64; }
    };

    stage(0);
    __syncthreads();

    for (int kt = 0; kt < 16; ++kt) {
        const int cur = kt & 1;
        if (kt < 15) stage(cur ^ 1);

        bfv8 af[2][2], bfr[4][2];
#pragma unroll
        for (int m = 0; m < 2; m++)
#pragma unroll
            for (int ks = 0; ks < 2; ks++)
                af[m][ks] = ldsfrag(As[cur], wr * 32 + m * 16 + c, ks * 4 + g);
#pragma unroll
        for (int n = 0; n < 4; n++)
#pragma unroll
            for (int ks = 0; ks < 2; ks++)
                bfr[n][ks] = ldsfrag(Bs[cur], wc * 64 + n * 16 + c, ks * 4 + g);
        __builtin_amdgcn_s_setprio(1);
#pragma unroll
        for (int m = 0; m < 2; m++)
#pragma unroll
            for (int n = 0; n < 4; n++)
#pragma unroll
                for (int ks = 0; ks < 2; ks++)
                    acc[m][n] = mfma16(af[m][ks], bfr[n][ks], acc[m][n]);
        __builtin_amdgcn_s_setprio(0);
        __syncthreads();
    }

#pragma unroll
    for (int n = 0; n < 4; n++) {
        const int gc = col0 + wc * 64 + n * 16 + c;
#pragma unroll
        for (int m = 0; m < 2; m++)
            gemm_store<EPI>(acc[m][n], row0 + wr * 32 + m * 16 + g * 4, gc,
                            bias, bscale, outp);
    }
}

// ---------------- GEMM core 128x128, double-buffered (4 waves 2Mx2N) ----------
template <int EPI>
DEV void gemm_body128(const short* __restrict__ A, const short* __restrict__ Bt,
                      const float* __restrict__ bias, void* __restrict__ outp,
                      float bscale, int row0, int col0, short (*As)[128 * 64],
                      short (*Bs)[128 * 64])
{
    const int t = threadIdx.x, lane = t & 63;
    const int wv = t >> 6, wr = wv >> 1, wc = wv & 1;
    const int g = lane >> 4, c = lane & 15;

    const f32x4 z4 = {0.f, 0.f, 0.f, 0.f};
    f32x4 acc[4][4];
#pragma unroll
    for (int m = 0; m < 4; m++)
#pragma unroll
        for (int n = 0; n < 4; n++) acc[m][n] = z4;

    const short* Ap[4]; const short* Bp[4]; int Cd[4];
#pragma unroll
    for (int j = 0; j < 4; j++) {
        int idx = j * 256 + t;
        int row = idx >> 3, sl = ((idx & 7) ^ (row & 7)) * 8;
        Ap[j] = A + row0 * 1024 + row * 1024 + sl;
        Bp[j] = Bt + col0 * 1024 + row * 1024 + sl;
        Cd[j] = idx * 8;
    }
    auto stage = [&](int buf) {
#pragma unroll
        for (int j = 0; j < 4; j++) {
            gload16(Ap[j], &As[buf][Cd[j]]); Ap[j] += 64;
            gload16(Bp[j], &Bs[buf][Cd[j]]); Bp[j] += 64;
        }
    };

    stage(0);
    __syncthreads();

    for (int kt = 0; kt < 16; ++kt) {
        const int cur = kt & 1;
        if (kt < 15) stage(cur ^ 1);

        bfv8 af[4][2], bfr[4][2];
#pragma unroll
        for (int m = 0; m < 4; m++)
#pragma unroll
            for (int ks = 0; ks < 2; ks++)
                af[m][ks] = ldsfrag(As[cur], wr * 64 + m * 16 + c, ks * 4 + g);
#pragma unroll
        for (int n = 0; n < 4; n++)
#pragma unroll
            for (int ks = 0; ks < 2; ks++)
                bfr[n][ks] = ldsfrag(Bs[cur], wc * 64 + n * 16 + c, ks * 4 + g);
        __builtin_amdgcn_s_setprio(1);
#pragma unroll
        for (int m = 0; m < 4; m++)
#pragma unroll
            for (int n = 0; n < 4; n++)
#pragma unroll
                for (int ks = 0; ks < 2; ks++)
                    acc[m][n] = mfma16(af[m][ks], bfr[n][ks], acc[m][n]);
        __builtin_amdgcn_s_setprio(0);
        __syncthreads();
    }

#pragma unroll
    for (int n = 0; n < 4; n++) {
        const int gc = col0 + wc * 64 + n * 16 + c;
#pragma unroll
        for (int m = 0; m < 4; m++)
            gemm_store<EPI>(acc[m][n], row0 + wr * 64 + m * 16 + g * 4, gc,
                            bias, bscale, outp);
    }
}

// fused QKV projection: grid (32, 24); 128x128 tiles; y/8 selects Q/K/V
__global__ __launch_bounds__(256, 2) void k_gemm3(
    const short* __restrict__ A,
    const short* __restrict__ WqT, const short* __restrict__ WkT, const short* __restrict__ WvT,
    const float* __restrict__ bq, const float* __restrict__ bk, const float* __restrict__ bv,
    short* __restrict__ Qs, short* __restrict__ Kst, short* __restrict__ Vts, float scq)
{
    __shared__ alignas(16) short As[2][128 * 64];
    __shared__ alignas(16) short Bs[2][128 * 64];
    const int which = blockIdx.y >> 3;
    const int col0 = (blockIdx.y & 7) * 128;
    const int row0 = blockIdx.x * 128;
    if (which == 0)
        gemm_body128<0>(A, WqT, bq, Qs, scq, row0, col0, As, Bs);
    else if (which == 1)
        gemm_body128<0>(A, WkT, bk, Kst, 1.f, row0, col0, As, Bs);
    else
        gemm_body128<1>(A, WvT, bv, Vts, 1.f, row0, col0, As, Bs);
}

// final projection (64x128 dbuf body)
__global__ __launch_bounds__(256, 2) void k_gemmO(
    const short* __restrict__ A, const short* __restrict__ Bt,
    const float* __restrict__ bias, float* __restrict__ outp)
{
    __shared__ alignas(16) short As[2][64 * 64];
    __shared__ alignas(16) short Bs[2][128 * 64];
    gemm_body<2>(A, Bt, bias, outp, 1.f, blockIdx.x * 64, blockIdx.y * 128, As, Bs);
}

// ---------------- flash attention, 32x32 MFMA, 8 waves x 32 q -----------------
// Q,K: [B,H,S,64] bf16 (Q pre-scaled by 0.125*log2e), Vt~: [B,H,64,S] bf16 with
// per-16-col bit3<->bit2 swap (epi 1), bbt: dense bias [(k>>3)][q][k&7] bf16.
// Ob: [B,S,1024] bf16. Grid (S/256, B*H) = 256 blocks, 512 threads (8 waves x
// 32 q-rows via mfma32), KV tile 64, dbuf LDS 32KB, 8 waves/CU.
// Halves LDS read traffic per q vs the 16x16 form (8 waves read each tile).
// Swapped ops: QK = mfma32(K,Q) -> lane owns q = lane&31; C/D layout:
// col=lane&31, row=(reg&3)+8*(reg>>2)+4*(lane>>5). Bias as C-init; exp2-domain
// softmax vs fixed max-estimate (post-PV corrected); row-sum via ones-mfma32;
// PV B-frags = consecutive sc regs packed via cvt_pk (slot-order-invariant:
// V~ pre-permutation makes contiguous A-reads deliver the matching k order).
__global__ __launch_bounds__(512, 1) void k_attn(
    const short* __restrict__ Q, const short* __restrict__ K,
    const short* __restrict__ Vt, const short* __restrict__ bbt,
    short* __restrict__ Ob)
{
    __shared__ alignas(16) short Ks[2][64 * 64];
    __shared__ alignas(16) short Vs[2][64 * 64];
    const int t = threadIdx.x, lane = t & 63;
    const int wv = t >> 6, qr = lane & 31, hi = lane >> 5;
    const int qt = blockIdx.x, bh = blockIdx.y;
    const int b = bh >> 4, h = bh & 15;
    const short* Qb = Q + bh * 2048 * 64;
    const short* Kb = K + bh * 2048 * 64;
    const short* Vb = Vt + bh * 64 * 2048;
    const int q0 = qt * 256 + wv * 32;
    const int qg = q0 + qr;

    // Q fragments (B-operand): qf[ks] = Q[qg][16ks + 8hi .. +7]
    bfv8 qf[4];
#pragma unroll
    for (int ks = 0; ks < 4; ks++)
        qf[ks] = *reinterpret_cast<const bfv8*>(Qb + qg * 64 + 16 * ks + 8 * hi);

    f32x16 oa[2];   // O^T d-tiles; elem r: d = 32dt + (r&3)+8*(r>>2)+4hi, col q
#pragma unroll
    for (int dt = 0; dt < 2; dt++)
#pragma unroll
        for (int r = 0; r < 16; r++) oa[dt][r] = 0.f;
    f32x16 lacc;
#pragma unroll
    for (int r = 0; r < 16; r++) lacc[r] = 0.f;
    float mrun = 20.0f;      // fixed max-estimate (logits bounded ~|12|)

    // ones A-fragment for the row-sum MFMA
    s8v ob_;
#pragma unroll
    for (int i = 0; i < 8; i++) ob_[i] = (short)0x3F80;
    const bfv8 ones = __builtin_bit_cast(bfv8, ob_);

    // staging: 512 K chunks + 512 V chunks, one of each per thread
    const int srow = t >> 3, ssl = ((t & 7) ^ (srow & 7)) * 8;
    const short* kp = Kb + srow * 64 + ssl;
    const short* vp = Vb + srow * 2048 + ssl;
    const int dst8 = t * 8;
    // dense bias: s4v at ((kt*8+g8)*2048 + qg)*8 + 4hi
    const short* bbp = bbt + (size_t)qg * 8 + 4 * hi;

    // fragment byte-offsets (shared by K tiles tt and V~ tiles dt)
    const int qx = qr & 7;
    int ofs[2][4];
#pragma unroll
    for (int tt = 0; tt < 2; tt++)
#pragma unroll
        for (int ks = 0; ks < 4; ks++)
            ofs[tt][ks] = (32 * tt + qr) * 128 + (((2 * ks + hi) ^ qx) << 4);

    // initial stage + bias prefetch
    gload16(kp, &Ks[0][dst8]);
    gload16(vp, &Vs[0][dst8]);
    kp += 4096; vp += 64;
    s4v bn[8];
#pragma unroll
    for (int g8 = 0; g8 < 8; g8++)
        bn[g8] = *reinterpret_cast<const s4v*>(bbp + g8 * 16384);
    bbp += 131072;
    __syncthreads();

    for (int kt = 0; kt < 32; ++kt) {
        const int cur = kt & 1;
        // bias -> C-init (reg 4u+v of tile tt <- bn[4tt+u][v])
        f32x16 sc0, sc1;
#pragma unroll
        for (int u = 0; u < 4; u++)
#pragma unroll
            for (int v = 0; v < 4; v++) {
                sc0[4 * u + v] = bf2f(bn[u][v]);
                sc1[4 * u + v] = bf2f(bn[4 + u][v]);
            }
        if (kt < 31) {
            const int nb = cur ^ 1;
            gload16(kp, &Ks[nb][dst8]);
            gload16(vp, &Vs[nb][dst8]);
            kp += 4096; vp += 64;
#pragma unroll
            for (int g8 = 0; g8 < 8; g8++)
                bn[g8] = *reinterpret_cast<const s4v*>(bbp + g8 * 16384);
            bbp += 131072;
        }

        const char* Kc = (const char*)&Ks[cur][0];
        const char* Vc = (const char*)&Vs[cur][0];

        // QK^T: two 32k x 32q C-tiles, bias pre-loaded as accumulator
        __builtin_amdgcn_s_setprio(1);
#pragma unroll
        for (int ks = 0; ks < 4; ks++)
            sc0 = mfma32(*reinterpret_cast<const bfv8*>(Kc + ofs[0][ks]), qf[ks], sc0);
#pragma unroll
        for (int ks = 0; ks < 4; ks++)
            sc1 = mfma32(*reinterpret_cast<const bfv8*>(Kc + ofs[1][ks]), qf[ks], sc1);
        __builtin_amdgcn_s_setprio(0);

        // speculative exp2 vs running max-estimate
#pragma unroll
        for (int r = 0; r < 16; r++) {
            sc0[r] = __builtin_amdgcn_exp2f(sc0[r] - mrun);
            sc1[r] = __builtin_amdgcn_exp2f(sc1[r] - mrun);
        }

        // pack P: pf[2tt+m] = regs 8m..8m+7 of sc_tt (matches V~ slot order)
        typedef struct { unsigned a, b, c2, d; } u4;
        bfv8 pf[4];
#pragma unroll
        for (int m = 0; m < 2; m++) {
            u4 w0, w1;
            w0.a = cvtpk(sc0[8 * m + 0], sc0[8 * m + 1]);
            w0.b = cvtpk(sc0[8 * m + 2], sc0[8 * m + 3]);
            w0.c2 = cvtpk(sc0[8 * m + 4], sc0[8 * m + 5]);
            w0.d = cvtpk(sc0[8 * m + 6], sc0[8 * m + 7]);
            pf[m] = __builtin_bit_cast(bfv8, w0);
            w1.a = cvtpk(sc1[8 * m + 0], sc1[8 * m + 1]);
            w1.b = cvtpk(sc1[8 * m + 2], sc1[8 * m + 3]);
            w1.c2 = cvtpk(sc1[8 * m + 4], sc1[8 * m + 5]);
            w1.d = cvtpk(sc1[8 * m + 6], sc1[8 * m + 7]);
            pf[2 + m] = __builtin_bit_cast(bfv8, w1);
        }

        // PV + row-sum: A-frags from permuted V~ (contiguous b128 reads)
        __builtin_amdgcn_s_setprio(1);
#pragma unroll
        for (int dt = 0; dt < 2; dt++)
#pragma unroll
            for (int cs = 0; cs < 4; cs++)
                oa[dt] = mfma32(*reinterpret_cast<const bfv8*>(Vc + ofs[dt][cs]),
                                pf[cs], oa[dt]);
#pragma unroll
        for (int cs = 0; cs < 4; cs++)
            lacc = mfma32(ones, pf[cs], lacc);
        __builtin_amdgcn_s_setprio(0);

        // deferred-max safety check in pe-domain (2^11.5 = 2896)
        float p0 = 0.f, p1 = 0.f;
#pragma unroll
        for (int u = 0; u < 4; u++) {
            p0 = fmaxf(p0, fmaxf(max3f(sc0[4 * u], sc0[4 * u + 1], sc0[4 * u + 2]),
                                 sc0[4 * u + 3]));
            p1 = fmaxf(p1, fmaxf(max3f(sc1[4 * u], sc1[4 * u + 1], sc1[4 * u + 2]),
                                 sc1[4 * u + 3]));
        }
        float pemax = fmaxf(p0, p1);
        if (!__all(pemax <= 2896.0f)) {   // rare: raise mrun, correct oa & lacc
            float rmax = fmaxf(pemax, __shfl_xor(pemax, 32));
            if (rmax > 2896.0f) {
                const float corr = 1.0f / rmax;
                mrun += __log2f(rmax);
#pragma unroll
                for (int dt = 0; dt < 2; dt++)
#pragma unroll
                    for (int r = 0; r < 16; r++) oa[dt][r] *= corr;
#pragma unroll
                for (int r = 0; r < 16; r++) lacc[r] *= corr;
            }
        }
        __syncthreads();
    }

    // epilogue: O^T -> Ob[B,S,1024]; d = 32dt + 8u + 4hi + v, 8B stores
    const float rl = 1.0f / lacc[0];
    short* Op = Ob + (size_t)(b * 2048 + qg) * 1024 + h * 64 + 4 * hi;
#pragma unroll
    for (int dt = 0; dt < 2; dt++)
#pragma unroll
        for (int u = 0; u < 4; u++) {
            s4v st;
#pragma unroll
            for (int v = 0; v < 4; v++) st[v] = f2bf(oa[dt][4 * u + v] * rl);
            *reinterpret_cast<s4v*>(Op + 32 * dt + 8 * u) = st;
        }
}

extern "C" void kernel_launch(void* const* d_in, const int* in_sizes, int n_in,
                              void* d_out, int out_size, void* d_ws, size_t ws_size,
                              hipStream_t stream)
{
    (void)in_sizes; (void)n_in; (void)out_size; (void)ws_size;
    const float* x    = (const float*)d_in[0];
    const float* bind = (const float*)d_in[1];
    const float* Wq   = (const float*)d_in[2];
    const float* bq   = (const float*)d_in[3];
    const float* Wk   = (const float*)d_in[4];
    const float* bk   = (const float*)d_in[5];
    const float* Wv   = (const float*)d_in[6];
    const float* bv   = (const float*)d_in[7];
    const float* Wo   = (const float*)d_in[8];
    const float* bo   = (const float*)d_in[9];

    char* ws = (char*)d_ws;
    const size_t MB = (size_t)1 << 20;
    short* xb   = (short*)(ws + 0 * MB);   // 8 MiB  x as bf16
    short* Wqt  = (short*)(ws + 8 * MB);   // 2 MiB  each, [n][k] bf16
    short* Wkt  = (short*)(ws + 10 * MB);
    short* Wvt  = (short*)(ws + 12 * MB);
    short* Wot  = (short*)(ws + 14 * MB);
    short* bbm  = (short*)(ws + 16 * MB);  // 8 MiB  dense bias bbt (k_cvtb)
    short* Qs   = (short*)(ws + 24 * MB);  // 8 MiB  [B,H,S,64]
    short* Kst  = (short*)(ws + 32 * MB);  // 8 MiB  [B,H,S,64]
    short* Vts  = (short*)(ws + 40 * MB);  // 8 MiB  [B,H,64,S] (bit3<->2 permuted)
    short* Obuf = (short*)(ws + 48 * MB);  // 8 MiB  [B,S,1024]

    const float LOG2E = 1.4426950408889634f;
    const float SCQ = 0.125f * LOG2E;   // hd^-0.5 * log2e, folded into Wq/bq
    const float SCB = 0.5f * LOG2E;     // binding_bias * log2e

    k_cvt<<<2048, 256, 0, stream>>>(x, xb, 1.f);
    k_cvtb<<<dim3(32, 32), 256, 0, stream>>>(bind, bbm, SCB);
    k_transpose4<<<dim3(32, 32, 4), 256, 0, stream>>>(Wq, Wk, Wv, Wo,
                                                      Wqt, Wkt, Wvt, Wot, SCQ);
    k_gemm3<<<dim3(32, 24), 256, 0, stream>>>(xb, Wqt, Wkt, Wvt, bq, bk, bv,
                                              Qs, Kst, Vts, SCQ);
    k_attn<<<dim3(8, 32), 512, 0, stream>>>(Qs, Kst, Vts, bbm, Obuf);
    k_gemmO<<<dim3(64, 8), 256, 0, stream>>>(Obuf, Wot, bo, (float*)d_out);
}

// Round 18
// 121.739 us; speedup vs baseline: 1.1360x; 1.1360x over previous
//
#include <hip/hip_runtime.h>

#define DEV static __device__ __forceinline__

typedef __attribute__((ext_vector_type(4))) float f32x4;
typedef __attribute__((ext_vector_type(8))) __bf16 bfv8;
typedef __attribute__((ext_vector_type(8))) short s8v;
typedef __attribute__((ext_vector_type(4))) short s4v;

DEV short f2bf(float f) {
    unsigned u = __float_as_uint(f);
    u = (u + 0x7fffu + ((u >> 16) & 1u)) >> 16;
    return (short)u;
}
DEV float bf2f(short s) { return __uint_as_float(((unsigned)(unsigned short)s) << 16); }

DEV void gload16(const void* g, void* l) {
    __builtin_amdgcn_global_load_lds(
        (const __attribute__((address_space(1))) void*)g,
        (__attribute__((address_space(3))) void*)l, 16, 0, 0);
}

DEV f32x4 mfma16(bfv8 a, bfv8 b, f32x4 c) {
    return __builtin_amdgcn_mfma_f32_16x16x32_bf16(a, b, c, 0, 0, 0);
}

DEV float max3f(float a, float b, float c) {
    float d;
    asm("v_max3_f32 %0, %1, %2, %3" : "=v"(d) : "v"(a), "v"(b), "v"(c));
    return d;
}
DEV unsigned cvtpk(float lo, float hi) {
    unsigned w;
    asm("v_cvt_pk_bf16_f32 %0, %1, %2" : "=v"(w) : "v"(lo), "v"(hi));
    return w;
}

// LDS tile layout: [row][8 slots of 8 bf16], physical slot = logical slot ^ (row&7)
DEV bfv8 ldsfrag(const short* base, int row, int slog) {
    int sp = slog ^ (row & 7);
    return *reinterpret_cast<const bfv8*>(base + row * 64 + sp * 8);
}

// ---------------- f32 -> bf16 elementwise (8 elems/thread, exact-fit grid) ----
__global__ void k_cvt(const float* __restrict__ in, short* __restrict__ out, float s) {
    int i = blockIdx.x * blockDim.x + threadIdx.x;
    const float4* p = (const float4*)in + (size_t)i * 2;
    float4 a = p[0], b = p[1];
    s8v o;
    o[0] = f2bf(a.x * s); o[1] = f2bf(a.y * s); o[2] = f2bf(a.z * s); o[3] = f2bf(a.w * s);
    o[4] = f2bf(b.x * s); o[5] = f2bf(b.y * s); o[6] = f2bf(b.z * s); o[7] = f2bf(b.w * s);
    reinterpret_cast<s8v*>(out)[i] = o;
}

// ---------------- bias transform: bb[S,S] f32 -> bbt[(kt*4+n)][q][16] bf16 -----
__global__ void k_cvtb(const float* __restrict__ in, short* __restrict__ out, float s) {
    int i = blockIdx.x * blockDim.x + threadIdx.x;   // 262144 threads
    int ktn = i >> 11, q = i & 2047;
    const float4* p = reinterpret_cast<const float4*>(in + (size_t)q * 2048 + ktn * 16);
    float4 a = p[0], b = p[1], cc = p[2], d = p[3];
    s8v o0, o1;
    o0[0] = f2bf(a.x * s); o0[1] = f2bf(a.y * s); o0[2] = f2bf(a.z * s); o0[3] = f2bf(a.w * s);
    o0[4] = f2bf(b.x * s); o0[5] = f2bf(b.y * s); o0[6] = f2bf(b.z * s); o0[7] = f2bf(b.w * s);
    o1[0] = f2bf(cc.x * s); o1[1] = f2bf(cc.y * s); o1[2] = f2bf(cc.z * s); o1[3] = f2bf(cc.w * s);
    o1[4] = f2bf(d.x * s); o1[5] = f2bf(d.y * s); o1[6] = f2bf(d.z * s); o1[7] = f2bf(d.w * s);
    s8v* dst = reinterpret_cast<s8v*>(out + (size_t)i * 16);
    dst[0] = o0; dst[1] = o1;
}

// ---------------- all four W [1024x1024] f32 -> Wt [n][k] bf16 (z selects) -----
__global__ void k_transpose4(
    const float* __restrict__ W0, const float* __restrict__ W1,
    const float* __restrict__ W2, const float* __restrict__ W3,
    short* __restrict__ T0, short* __restrict__ T1,
    short* __restrict__ T2, short* __restrict__ T3, float s0)
{
    __shared__ float tl[32][33];
    const int z = blockIdx.z;
    const float* W = z == 0 ? W0 : z == 1 ? W1 : z == 2 ? W2 : W3;
    short* Wt = z == 0 ? T0 : z == 1 ? T1 : z == 2 ? T2 : T3;
    const float s = z == 0 ? s0 : 1.f;
    int tx = threadIdx.x & 31, ty = threadIdx.x >> 5;
    int nb = blockIdx.x * 32, kb = blockIdx.y * 32;
#pragma unroll
    for (int i = 0; i < 4; i++)
        tl[ty + i * 8][tx] = W[(kb + ty + i * 8) * 1024 + nb + tx];
    __syncthreads();
#pragma unroll
    for (int i = 0; i < 4; i++)
        Wt[(nb + ty + i * 8) * 1024 + kb + tx] = f2bf(tl[tx][ty + i * 8] * s);
}

// ---------------- GEMM epilogue (shared) --------------------------------------
// epi 0: bf16 [B,H,S,Hd]; epi 1: bf16 [B,H,Hd,S] (V^T, k-bit-shuffled per 64-col
// tile: bits {5,1,0} keep, {3,2}<<1, {4}>>2); epi 2: f32 row-major.
template <int EPI>
DEV void gemm_store(f32x4 a4, int gr, int gc, const float* bias, float bscale,
                    void* outp)
{
    const float bvl = bias[gc] * bscale;
    const int h = gc >> 6, d = gc & 63;
    if (EPI == 2) {
        float* O = (float*)outp;
#pragma unroll
        for (int r = 0; r < 4; r++) O[(gr + r) * 1024 + gc] = a4[r] + bvl;
    } else {
        const int b = gr >> 11, sr = gr & 2047;
        short* O = (short*)outp;
        if (EPI == 0) {
            int base = ((b * 16 + h) * 2048 + sr) * 64 + d;
#pragma unroll
            for (int r = 0; r < 4; r++) O[base + r * 64] = f2bf(a4[r] + bvl);
        } else {
            s4v vv;
#pragma unroll
            for (int r = 0; r < 4; r++) vv[r] = f2bf(a4[r] + bvl);
            const int s6 = sr & 63;
            const int qp = (sr & ~63) | (s6 & 35) | ((s6 & 12) << 1) | ((s6 & 16) >> 2);
            *reinterpret_cast<s4v*>(O + ((b * 16 + h) * 64 + d) * 2048 + qp) = vv;
        }
    }
}

// ---------------- GEMM core 64x128 (4 waves 2Mx2N) ----------------------------
template <int EPI>
DEV void gemm_body(const short* __restrict__ A, const short* __restrict__ Bt,
                   const float* __restrict__ bias, void* __restrict__ outp,
                   float bscale, int row0, int col0, short* As, short* Bs)
{
    const int t = threadIdx.x, lane = t & 63;
    const int wv = t >> 6, wr = wv >> 1, wc = wv & 1;
    const int g = lane >> 4, c = lane & 15;

    const f32x4 z4 = {0.f, 0.f, 0.f, 0.f};
    f32x4 acc[2][4];
#pragma unroll
    for (int m = 0; m < 2; m++)
#pragma unroll
        for (int n = 0; n < 4; n++) acc[m][n] = z4;

    for (int kt = 0; kt < 16; ++kt) {
        const int k0 = kt * 64;
        const short* Ag = A + row0 * 1024 + k0;
        const short* Bg = Bt + col0 * 1024 + k0;
#pragma unroll
        for (int j = 0; j < 2; j++) {
            int idx = j * 256 + t;
            int row = idx >> 3, sp = idx & 7, sl = sp ^ (row & 7);
            gload16(Ag + row * 1024 + sl * 8, As + idx * 8);
        }
#pragma unroll
        for (int j = 0; j < 4; j++) {
            int idx = j * 256 + t;
            int row = idx >> 3, sp = idx & 7, sl = sp ^ (row & 7);
            gload16(Bg + row * 1024 + sl * 8, Bs + idx * 8);
        }
        __syncthreads();

        bfv8 af[2][2], bfr[4][2];
#pragma unroll
        for (int m = 0; m < 2; m++)
#pragma unroll
            for (int ks = 0; ks < 2; ks++)
                af[m][ks] = ldsfrag(As, wr * 32 + m * 16 + c, ks * 4 + g);
#pragma unroll
        for (int n = 0; n < 4; n++)
#pragma unroll
            for (int ks = 0; ks < 2; ks++)
                bfr[n][ks] = ldsfrag(Bs, wc * 64 + n * 16 + c, ks * 4 + g);
        __builtin_amdgcn_s_setprio(1);
#pragma unroll
        for (int m = 0; m < 2; m++)
#pragma unroll
            for (int n = 0; n < 4; n++)
#pragma unroll
                for (int ks = 0; ks < 2; ks++)
                    acc[m][n] = mfma16(af[m][ks], bfr[n][ks], acc[m][n]);
        __builtin_amdgcn_s_setprio(0);
        __syncthreads();
    }

#pragma unroll
    for (int n = 0; n < 4; n++) {
        const int gc = col0 + wc * 64 + n * 16 + c;
#pragma unroll
        for (int m = 0; m < 2; m++)
            gemm_store<EPI>(acc[m][n], row0 + wr * 32 + m * 16 + g * 4, gc,
                            bias, bscale, outp);
    }
}

// ---------------- GEMM core 128x128 (4 waves 2Mx2N, 64x64 acc each) -----------
template <int EPI>
DEV void gemm_body128(const short* __restrict__ A, const short* __restrict__ Bt,
                      const float* __restrict__ bias, void* __restrict__ outp,
                      float bscale, int row0, int col0, short* As, short* Bs)
{
    const int t = threadIdx.x, lane = t & 63;
    const int wv = t >> 6, wr = wv >> 1, wc = wv & 1;
    const int g = lane >> 4, c = lane & 15;

    const f32x4 z4 = {0.f, 0.f, 0.f, 0.f};
    f32x4 acc[4][4];
#pragma unroll
    for (int m = 0; m < 4; m++)
#pragma unroll
        for (int n = 0; n < 4; n++) acc[m][n] = z4;

    for (int kt = 0; kt < 16; ++kt) {
        const int k0 = kt * 64;
        const short* Ag = A + row0 * 1024 + k0;
        const short* Bg = Bt + col0 * 1024 + k0;
#pragma unroll
        for (int j = 0; j < 4; j++) {
            int idx = j * 256 + t;
            int row = idx >> 3, sp = idx & 7, sl = sp ^ (row & 7);
            gload16(Ag + row * 1024 + sl * 8, As + idx * 8);
            gload16(Bg + row * 1024 + sl * 8, Bs + idx * 8);
        }
        __syncthreads();

        bfv8 af[4][2], bfr[4][2];
#pragma unroll
        for (int m = 0; m < 4; m++)
#pragma unroll
            for (int ks = 0; ks < 2; ks++)
                af[m][ks] = ldsfrag(As, wr * 64 + m * 16 + c, ks * 4 + g);
#pragma unroll
        for (int n = 0; n < 4; n++)
#pragma unroll
            for (int ks = 0; ks < 2; ks++)
                bfr[n][ks] = ldsfrag(Bs, wc * 64 + n * 16 + c, ks * 4 + g);
        __builtin_amdgcn_s_setprio(1);
#pragma unroll
        for (int m = 0; m < 4; m++)
#pragma unroll
            for (int n = 0; n < 4; n++)
#pragma unroll
                for (int ks = 0; ks < 2; ks++)
                    acc[m][n] = mfma16(af[m][ks], bfr[n][ks], acc[m][n]);
        __builtin_amdgcn_s_setprio(0);
        __syncthreads();
    }

#pragma unroll
    for (int n = 0; n < 4; n++) {
        const int gc = col0 + wc * 64 + n * 16 + c;
#pragma unroll
        for (int m = 0; m < 4; m++)
            gemm_store<EPI>(acc[m][n], row0 + wr * 64 + m * 16 + g * 4, gc,
                            bias, bscale, outp);
    }
}

// fused QKV projection: grid (32, 24); 128x128 tiles; y/8 selects Q/K/V
__global__ __launch_bounds__(256, 2) void k_gemm3(
    const short* __restrict__ A,
    const short* __restrict__ WqT, const short* __restrict__ WkT, const short* __restrict__ WvT,
    const float* __restrict__ bq, const float* __restrict__ bk, const float* __restrict__ bv,
    short* __restrict__ Qs, short* __restrict__ Kst, short* __restrict__ Vts, float scq)
{
    __shared__ alignas(16) short As[128 * 64];
    __shared__ alignas(16) short Bs[128 * 64];
    const int which = blockIdx.y >> 3;
    const int col0 = (blockIdx.y & 7) * 128;
    const int row0 = blockIdx.x * 128;
    if (which == 0)
        gemm_body128<0>(A, WqT, bq, Qs, scq, row0, col0, As, Bs);
    else if (which == 1)
        gemm_body128<0>(A, WkT, bk, Kst, 1.f, row0, col0, As, Bs);
    else
        gemm_body128<1>(A, WvT, bv, Vts, 1.f, row0, col0, As, Bs);
}

// final projection (64x128 body; 512 blocks keeps occupancy)
__global__ __launch_bounds__(256, 2) void k_gemmO(
    const short* __restrict__ A, const short* __restrict__ Bt,
    const float* __restrict__ bias, float* __restrict__ outp)
{
    __shared__ alignas(16) short As[64 * 64];
    __shared__ alignas(16) short Bs[128 * 64];
    gemm_body<2>(A, Bt, bias, outp, 1.f, blockIdx.x * 64, blockIdx.y * 128, As, Bs);
}

// ---------------- flash attention, 16 waves x 16 q, in-register P -------------
// Q,K: [B,H,S,64] bf16 (Q pre-scaled by 0.125*log2e), Vt~: [B,H,64,S] bf16 with
// per-64-tile k-permutation baked in (epi 1), bbt: coalesced bias (k_cvtb).
// Ob: [B,S,1024] bf16. Grid (S/256, B*H) = 256 blocks, 1024 threads (16 waves x
// 16 q-rows), KV tile 64, dbuf LDS 32KB -> 1 block/CU (16 waves/CU).
// Staging: ONE gload16 per thread per iter (waves 0-7 stage K, 8-15 stage V).
// Bias as QK accumulator init; exp2-domain softmax vs fixed max-estimate
// (post-PV corrected); row-sum via ones-MFMA; PV B-frags direct from cvt_pk
// regs (k-permutation baked into V~).
__global__ __launch_bounds__(1024, 4) void k_attn(
    const short* __restrict__ Q, const short* __restrict__ K,
    const short* __restrict__ Vt, const short* __restrict__ bbt,
    short* __restrict__ Ob)
{
    __shared__ alignas(16) short Ks[2][64 * 64];
    __shared__ alignas(16) short Vs[2][64 * 64];
    const int t = threadIdx.x, lane = t & 63;
    const int wv = t >> 6, g = lane >> 4, c = lane & 15;
    const int qt = blockIdx.x, bh = blockIdx.y;
    const int b = bh >> 4, h = bh & 15;
    const short* Qb = Q + bh * 2048 * 64;
    const short* Kb = K + bh * 2048 * 64;
    const short* Vb = Vt + bh * 64 * 2048;
    const int q0 = qt * 256 + wv * 16;

    // Q fragments (second-operand layout): lane holds Q row (q0+c)
    bfv8 qf[2];
#pragma unroll
    for (int ks = 0; ks < 2; ks++)
        qf[ks] = *reinterpret_cast<const bfv8*>(Qb + (q0 + c) * 64 + ks * 32 + g * 8);

    const f32x4 z4 = {0.f, 0.f, 0.f, 0.f};
    f32x4 oa[4];             // [nd]; elem r: O^T[d=nd*16+4g+r][q=q0+c]
#pragma unroll
    for (int nd = 0; nd < 4; nd++) oa[nd] = z4;
    f32x4 lacc = z4;         // row-sum accumulator via ones-MFMA
    float mrun = 20.0f;      // fixed max-estimate (logits bounded ~|12|)

    // ones A-fragment for the row-sum MFMA
    s8v ob_;
#pragma unroll
    for (int i = 0; i < 8; i++) ob_[i] = (short)0x3F80;
    const bfv8 ones = __builtin_bit_cast(bfv8, ob_);

    // staging: 1024 chunks/tile (512 K + 512 V), one per thread
    const bool isK = t < 512;
    const int sidx = isK ? t : t - 512;
    const int srow = sidx >> 3, ssl = ((sidx & 7) ^ (srow & 7)) * 8;
    const short* sp_ = isK ? (Kb + srow * 64 + ssl) : (Vb + srow * 2048 + ssl);
    const int sinc = isK ? 4096 : 64;
    const int dst8 = sidx * 8;
    // coalesced bias: element ((kt*4+n)*2048 + q0+c)*16 + 4g
    const short* bbp = bbt + (size_t)(q0 + c) * 16 + 4 * g;

    // hoisted LDS frag byte-offsets (same pattern for K and V~ tiles)
    const int cx = c & 7;
    const int fofs0 = c * 128 + ((g ^ cx) << 4);
    const int fofs1 = c * 128 + (((4 + g) ^ cx) << 4);

    // initial stage + bias prefetch
    gload16(sp_, isK ? &Ks[0][dst8] : &Vs[0][dst8]);
    sp_ += sinc;
    s4v bn[4];
#pragma unroll
    for (int n = 0; n < 4; n++)
        bn[n] = *reinterpret_cast<const s4v*>(bbp + n * 32768);
    bbp += 131072;
    __syncthreads();

    for (int kt = 0; kt < 32; ++kt) {
        const int cur = kt & 1;
        // consume bias prefetch -> f32 C-init fragments
        f32x4 cb[4];
#pragma unroll
        for (int n = 0; n < 4; n++)
#pragma unroll
            for (int r = 0; r < 4; r++) cb[n][r] = bf2f(bn[n][r]);
        if (kt < 31) {
            const int nb = cur ^ 1;
            gload16(sp_, isK ? &Ks[nb][dst8] : &Vs[nb][dst8]);
            sp_ += sinc;
#pragma unroll
            for (int n = 0; n < 4; n++)
                bn[n] = *reinterpret_cast<const s4v*>(bbp + n * 32768);
            bbp += 131072;
        }

        const char* Kc = (const char*)&Ks[cur][0];
        const char* Vc = (const char*)&Vs[cur][0];

        // S^T tile with bias as accumulator init: sc[n][r] = bias + QK
        f32x4 sc[4];
        __builtin_amdgcn_s_setprio(1);
#pragma unroll
        for (int n = 0; n < 4; n++) {
            bfv8 k0 = *reinterpret_cast<const bfv8*>(Kc + fofs0 + n * 2048);
            bfv8 k1 = *reinterpret_cast<const bfv8*>(Kc + fofs1 + n * 2048);
            sc[n] = mfma16(k0, qf[0], cb[n]);
            sc[n] = mfma16(k1, qf[1], sc[n]);
        }
        __builtin_amdgcn_s_setprio(0);

        // speculative exp2 against running max-estimate (no branch wait)
#pragma unroll
        for (int n = 0; n < 4; n++)
#pragma unroll
            for (int r = 0; r < 4; r++)
                sc[n][r] = __builtin_amdgcn_exp2f(sc[n][r] - mrun);

        // pack P words in-register; B-frags in permuted k-order (matches V~)
        unsigned w0[4], w1[4];
#pragma unroll
        for (int n = 0; n < 4; n++) {
            w0[n] = cvtpk(sc[n][0], sc[n][1]);
            w1[n] = cvtpk(sc[n][2], sc[n][3]);
        }
        typedef struct { unsigned a, b, c2, d; } u4;
        u4 q0w; q0w.a = w0[0]; q0w.b = w1[0]; q0w.c2 = w0[1]; q0w.d = w1[1];
        u4 q1w; q1w.a = w0[2]; q1w.b = w1[2]; q1w.c2 = w0[3]; q1w.d = w1[3];
        const bfv8 pf0 = __builtin_bit_cast(bfv8, q0w);
        const bfv8 pf1 = __builtin_bit_cast(bfv8, q1w);

        // PV + row-sum: A-frags from permuted V~ via standard b128 reads
        __builtin_amdgcn_s_setprio(1);
#pragma unroll
        for (int nd = 0; nd < 4; nd++) {
            bfv8 v0 = *reinterpret_cast<const bfv8*>(Vc + fofs0 + nd * 2048);
            bfv8 v1 = *reinterpret_cast<const bfv8*>(Vc + fofs1 + nd * 2048);
            oa[nd] = mfma16(v0, pf0, oa[nd]);
            oa[nd] = mfma16(v1, pf1, oa[nd]);
        }
        lacc = mfma16(ones, pf0, lacc);
        lacc = mfma16(ones, pf1, lacc);
        __builtin_amdgcn_s_setprio(0);

        // deferred-max safety check in pe-domain (2^11.5 = 2896)
        float t0 = fmaxf(max3f(sc[0][0], sc[0][1], sc[0][2]), sc[0][3]);
        float t1 = fmaxf(max3f(sc[1][0], sc[1][1], sc[1][2]), sc[1][3]);
        float t2 = fmaxf(max3f(sc[2][0], sc[2][1], sc[2][2]), sc[2][3]);
        float t3 = fmaxf(max3f(sc[3][0], sc[3][1], sc[3][2]), sc[3][3]);
        float pemax = fmaxf(max3f(t0, t1, t2), t3);
        if (!__all(pemax <= 2896.0f)) {   // rare: raise mrun, correct oa & lacc
            float rmax = fmaxf(pemax, __shfl_xor(pemax, 16));
            rmax = fmaxf(rmax, __shfl_xor(rmax, 32));
            if (rmax > 2896.0f) {
                const float corr = 1.0f / rmax;
                mrun += __log2f(rmax);
#pragma unroll
                for (int nd = 0; nd < 4; nd++)
#pragma unroll
                    for (int r = 0; r < 4; r++) oa[nd][r] *= corr;
#pragma unroll
                for (int r = 0; r < 4; r++) lacc[r] *= corr;
            }
        }
        __syncthreads();
    }

    // epilogue: O^T frag -> Ob[B,S,1024], 8B stores
    const float rl = 1.0f / lacc[0];
    const size_t orow = (size_t)(b * 2048 + q0 + c);
#pragma unroll
    for (int nd = 0; nd < 4; nd++) {
        s4v st;
#pragma unroll
        for (int r = 0; r < 4; r++) st[r] = f2bf(oa[nd][r] * rl);
        *reinterpret_cast<s4v*>(Ob + orow * 1024 + h * 64 + nd * 16 + 4 * g) = st;
    }
}

extern "C" void kernel_launch(void* const* d_in, const int* in_sizes, int n_in,
                              void* d_out, int out_size, void* d_ws, size_t ws_size,
                              hipStream_t stream)
{
    (void)in_sizes; (void)n_in; (void)out_size; (void)ws_size;
    const float* x    = (const float*)d_in[0];
    const float* bind = (const float*)d_in[1];
    const float* Wq   = (const float*)d_in[2];
    const float* bq   = (const float*)d_in[3];
    const float* Wk   = (const float*)d_in[4];
    const float* bk   = (const float*)d_in[5];
    const float* Wv   = (const float*)d_in[6];
    const float* bv   = (const float*)d_in[7];
    const float* Wo   = (const float*)d_in[8];
    const float* bo   = (const float*)d_in[9];

    char* ws = (char*)d_ws;
    const size_t MB = (size_t)1 << 20;
    short* xb   = (short*)(ws + 0 * MB);   // 8 MiB  x as bf16
    short* Wqt  = (short*)(ws + 8 * MB);   // 2 MiB  each, [n][k] bf16
    short* Wkt  = (short*)(ws + 10 * MB);
    short* Wvt  = (short*)(ws + 12 * MB);
    short* Wot  = (short*)(ws + 14 * MB);
    short* bbm  = (short*)(ws + 16 * MB);  // 8 MiB  coalesced bias bbt (k_cvtb)
    short* Qs   = (short*)(ws + 24 * MB);  // 8 MiB  [B,H,S,64]
    short* Kst  = (short*)(ws + 32 * MB);  // 8 MiB  [B,H,S,64]
    short* Vts  = (short*)(ws + 40 * MB);  // 8 MiB  [B,H,64,S] (k-permuted)
    short* Obuf = (short*)(ws + 48 * MB);  // 8 MiB  [B,S,1024]

    const float LOG2E = 1.4426950408889634f;
    const float SCQ = 0.125f * LOG2E;   // hd^-0.5 * log2e, folded into Wq/bq
    const float SCB = 0.5f * LOG2E;     // binding_bias * log2e

    k_cvt<<<2048, 256, 0, stream>>>(x, xb, 1.f);
    k_cvtb<<<1024, 256, 0, stream>>>(bind, bbm, SCB);
    k_transpose4<<<dim3(32, 32, 4), 256, 0, stream>>>(Wq, Wk, Wv, Wo,
                                                      Wqt, Wkt, Wvt, Wot, SCQ);
    k_gemm3<<<dim3(32, 24), 256, 0, stream>>>(xb, Wqt, Wkt, Wvt, bq, bk, bv,
                                              Qs, Kst, Vts, SCQ);
    k_attn<<<dim3(8, 32), 1024, 0, stream>>>(Qs, Kst, Vts, bbm, Obuf);
    k_gemmO<<<dim3(64, 8), 256, 0, stream>>>(Obuf, Wot, bo, (float*)d_out);
}